// Round 4
// baseline (133.344 us; speedup 1.0000x reference)
//
#include <hip/hip_runtime.h>
#include <hip/hip_bf16.h>

// Problem constants
#define B_N   8192
#define OBS   128
#define HID   512
#define VSZ   256
#define NU    64
#define TOPK  8
#define NOPT  16
#define KEXT  160   // 128 x-cols + 1 bias col + 31 zero pad
#define NBLK  128   // persistent grid: always co-resident on 256 CUs

typedef __bf16 bf16_t;
typedef __bf16 bf16x8 __attribute__((ext_vector_type(8)));
typedef float  f32x4  __attribute__((ext_vector_type(4)));

// Workspace layout (bytes)
#define OFF_FLAGS 0u        // 2 x u32 barrier counters (memset to 0 each call)
#define OFF_A     128u      // 16 f32
#define OFF_DP    256u      // 256 f32
#define OFF_WT    2048u     // wefft[v][j] f32 256x512 = 524288
#define OFF_MT    526336u   // mt[v][k] bf16 256x160 = 81920

// Device-scope grid barrier (counter pre-zeroed via hipMemsetAsync node).
// Release: fence + relaxed RMW; acquire: spin RMW + fence. tid0's acquire
// fence invalidates the CU's L1 + XCD L2, covering the whole block.
__device__ __forceinline__ void gbar(unsigned* cnt) {
    __syncthreads();
    if (threadIdx.x == 0) {
        __threadfence();
        atomicAdd(cnt, 1u);
        while (atomicAdd(cnt, 0u) < (unsigned)NBLK)
            __builtin_amdgcn_s_sleep(1);
        __threadfence();
    }
    __syncthreads();
}

__launch_bounds__(256)
__global__ void k_fused(const float* __restrict__ x, const int* __restrict__ opt,
                        const float* __restrict__ pw, const float* __restrict__ pb,
                        const float* __restrict__ vw, const float* __restrict__ vb,
                        const float* __restrict__ p_w, const float* __restrict__ p_b,
                        float* __restrict__ out, char* __restrict__ ws) {
    unsigned* flags = (unsigned*)(ws + OFF_FLAGS);
    float*    A     = (float*)   (ws + OFF_A);
    float*    Dp    = (float*)   (ws + OFF_DP);
    float*    wefft = (float*)   (ws + OFF_WT);
    bf16_t*   mt    = (bf16_t*)  (ws + OFF_MT);

    const int tid  = threadIdx.x;
    const int lane = tid & 63;
    const int wv   = tid >> 6;

    __shared__ float kbuf[2][132];

    // ---------------- Phase 1: wefft[v][j] = 0.25*sum_h vw[j][h*256+v]; A; Dp
    {
        int j0 = blockIdx.x * 4;            // 4 j-rows per block, 128*4 = 512
        float vals[4];
        #pragma unroll
        for (int jj = 0; jj < 4; ++jj) {
            const float* r = vw + (j0 + jj) * (4 * VSZ);
            vals[jj] = 0.25f * ((r[tid] + r[tid + 256]) + (r[tid + 512] + r[tid + 768]));
        }
        f32x4 o = {vals[0], vals[1], vals[2], vals[3]};
        *(f32x4*)(wefft + tid * HID + j0) = o;

        if (blockIdx.x == 0) {
            // A[opt]: wave wv handles options 4wv..4wv+3
            #pragma unroll
            for (int oo = 0; oo < 4; ++oo) {
                int o_ = wv * 4 + oo;
                float cur = p_w[o_ * NU + lane] + p_b[lane];
                float sum = 0.f;
                #pragma unroll
                for (int t = 0; t < TOPK; ++t) {
                    float m = cur;
                    #pragma unroll
                    for (int off = 32; off >= 1; off >>= 1)
                        m = fmaxf(m, __shfl_xor(m, off));
                    sum += 1.f / (1.f + expf(-m));
                    unsigned long long bal = __ballot(cur == m);
                    int first = __ffsll(bal) - 1;   // lowest index: jax tie-break
                    if (lane == first) cur = -1e30f;
                }
                if (lane == 0) A[o_] = sum * (1.f / NU);
            }
            Dp[tid] = 0.03125f * ((vb[tid] + vb[tid + 256]) + (vb[tid + 512] + vb[tid + 768]));
        }
    }
    gbar(flags + 0);

    // ---------------- Phase 2: mt[v][k] = sum_j pw[k][j]*wefft[v][j] (+c, +pad)
    {
        int v0 = blockIdx.x * 2;            // 2 v-rows per block
        const float* wfp0 = wefft + v0 * HID + lane * 8;
        const float* wfp1 = wfp0 + HID;
        f32x4 w00 = *(const f32x4*)(wfp0),     w01 = *(const f32x4*)(wfp0 + 4);
        f32x4 w10 = *(const f32x4*)(wfp1),     w11 = *(const f32x4*)(wfp1 + 4);

        for (int it = 0; it < 33; ++it) {
            if (it == 32 && wv != 0) break;             // only wave 0 does c row
            const float* pr = (it < 32) ? (pw + (wv * 32 + it) * HID + lane * 8)
                                        : (pb + lane * 8);
            f32x4 p0 = *(const f32x4*)(pr), p1 = *(const f32x4*)(pr + 4);
            float s0 = ((p0[0]*w00[0] + p0[1]*w00[1]) + (p0[2]*w00[2] + p0[3]*w00[3]))
                     + ((p1[0]*w01[0] + p1[1]*w01[1]) + (p1[2]*w01[2] + p1[3]*w01[3]));
            float s1 = ((p0[0]*w10[0] + p0[1]*w10[1]) + (p0[2]*w10[2] + p0[3]*w10[3]))
                     + ((p1[0]*w11[0] + p1[1]*w11[1]) + (p1[2]*w11[2] + p1[3]*w11[3]));
            #pragma unroll
            for (int off = 32; off >= 1; off >>= 1) {
                s0 += __shfl_xor(s0, off);
                s1 += __shfl_xor(s1, off);
            }
            if (lane == 0) {
                int k = (it < 32) ? (wv * 32 + it) : 128;
                kbuf[0][k] = s0;
                kbuf[1][k] = s1;
            }
        }
        __syncthreads();
        #pragma unroll
        for (int idx = tid; idx < 2 * KEXT; idx += 256) {
            int vv = idx / KEXT;
            int k  = idx - vv * KEXT;
            float val = (k < 129) ? kbuf[vv][k] : 0.f;
            mt[(v0 + vv) * KEXT + k] = (bf16_t)val;
        }
    }
    gbar(flags + 1);

    // ---------------- Phase 3: out[b][v] = A[opt[b]]*(x'@M')[b][v] + Dp[v]
    {
        const int mrow = lane & 15;
        const int quad = lane >> 4;
        const int r0   = blockIdx.x * 64 + wv * 16;   // 64 rows/block

        // A-fragments for all 5 k-tiles, loaded once (x read exactly once)
        bf16x8 af[5];
        const float* xr = x + (r0 + mrow) * OBS + quad * 8;
        #pragma unroll
        for (int kt = 0; kt < 4; ++kt) {
            f32x4 lo = *(const f32x4*)(xr + kt * 32);
            f32x4 hi = *(const f32x4*)(xr + kt * 32 + 4);
            bf16x8 a;
            a[0] = (bf16_t)lo[0]; a[1] = (bf16_t)lo[1];
            a[2] = (bf16_t)lo[2]; a[3] = (bf16_t)lo[3];
            a[4] = (bf16_t)hi[0]; a[5] = (bf16_t)hi[1];
            a[6] = (bf16_t)hi[2]; a[7] = (bf16_t)hi[3];
            af[kt] = a;
        }
        {
            bf16x8 a;
            #pragma unroll
            for (int j = 0; j < 8; ++j) a[j] = (bf16_t)0.f;
            if (quad == 0) a[0] = (bf16_t)1.0f;       // k=128: bias column
            af[4] = a;
        }

        #pragma unroll
        for (int half = 0; half < 2; ++half) {
            int c0 = half * 128;
            f32x4 acc[8];
            #pragma unroll
            for (int t = 0; t < 8; ++t) acc[t] = (f32x4){0.f, 0.f, 0.f, 0.f};
            const bf16_t* mb = mt + (c0 + mrow) * KEXT + quad * 8;
            #pragma unroll
            for (int kt = 0; kt < 5; ++kt) {
                #pragma unroll
                for (int t = 0; t < 8; ++t) {
                    bf16x8 b = *(const bf16x8*)(mb + t * 16 * KEXT + kt * 32);
                    acc[t] = __builtin_amdgcn_mfma_f32_16x16x32_bf16(af[kt], b, acc[t], 0, 0, 0);
                }
            }
            // C/D layout: col=lane&15, row=quad*4+reg
            #pragma unroll
            for (int r = 0; r < 4; ++r) {
                int row = r0 + quad * 4 + r;
                float av = A[opt[row]];
                float* orow = out + row * VSZ;
                #pragma unroll
                for (int t = 0; t < 8; ++t) {
                    int col = c0 + t * 16 + mrow;
                    orow[col] = av * acc[t][r] + Dp[col];
                }
            }
        }
    }
}

// ---------------------------------------------------------------------------
extern "C" void kernel_launch(void* const* d_in, const int* in_sizes, int n_in,
                              void* d_out, int out_size, void* d_ws, size_t ws_size,
                              hipStream_t stream) {
    const float* x        = (const float*)d_in[0];
    const int*   option   = (const int*)  d_in[1];
    const float* pre_fc_w = (const float*)d_in[2];
    const float* pre_fc_b = (const float*)d_in[3];
    const float* value_w  = (const float*)d_in[4];
    const float* value_b  = (const float*)d_in[5];
    const float* p_w      = (const float*)d_in[6];
    const float* p_b      = (const float*)d_in[7];
    float* out = (float*)d_out;
    char*  ws  = (char*)d_ws;

    // zero the two barrier counters (graph-capturable memset node)
    hipMemsetAsync(ws + OFF_FLAGS, 0, 8, stream);

    k_fused<<<dim3(NBLK), dim3(256), 0, stream>>>(
        x, option, pre_fc_w, pre_fc_b, value_w, value_b, p_w, p_b, out, ws);
}

// Round 5
// 132.729 us; speedup vs baseline: 1.0046x; 1.0046x over previous
//
#include <hip/hip_runtime.h>
#include <hip/hip_bf16.h>

// Problem constants
#define B_N   8192
#define OBS   128
#define HID   512
#define VSZ   256
#define NU    64
#define TOPK  8
#define NOPT  16
#define KEXT  160   // 128 x-cols + 1 bias col + 31 zero pad
#define NBLK  128   // persistent grid: always co-resident on 256 CUs

typedef __bf16 bf16_t;
typedef __bf16 bf16x8 __attribute__((ext_vector_type(8)));
typedef float  f32x4  __attribute__((ext_vector_type(4)));

// Workspace layout (bytes)
#define OFF_FLAG0 0u        // barrier counter 0 (own 128B line)
#define OFF_FLAG1 512u      // barrier counter 1 (own 128B line)
#define OFF_A     1024u     // 16 f32
#define OFF_DP    1280u     // 256 f32
#define OFF_WT    4096u     // wefft[v][j] f32 256x512 = 524288
#define OFF_MT    528384u   // mt[v][k] bf16 256x160 = 81920

// Grid barrier: one relaxed RMW arrive per block, then LOAD-spin (no RMW
// serialization at the coherence point), agent-scope fences at the edges.
__device__ __forceinline__ void gbar(unsigned* cnt) {
    __syncthreads();
    if (threadIdx.x == 0) {
        __threadfence();   // release prior writes
        __hip_atomic_fetch_add(cnt, 1u, __ATOMIC_RELAXED, __HIP_MEMORY_SCOPE_AGENT);
        while (__hip_atomic_load(cnt, __ATOMIC_RELAXED, __HIP_MEMORY_SCOPE_AGENT)
               < (unsigned)NBLK)
            __builtin_amdgcn_s_sleep(4);
        __threadfence();   // acquire others' writes
    }
    __syncthreads();
}

__launch_bounds__(256)
__global__ void k_fused(const float* __restrict__ x, const int* __restrict__ opt,
                        const float* __restrict__ pw, const float* __restrict__ pb,
                        const float* __restrict__ vw, const float* __restrict__ vb,
                        const float* __restrict__ p_w, const float* __restrict__ p_b,
                        float* __restrict__ out, char* __restrict__ ws) {
    unsigned* flag0 = (unsigned*)(ws + OFF_FLAG0);
    unsigned* flag1 = (unsigned*)(ws + OFF_FLAG1);
    float*    A     = (float*)   (ws + OFF_A);
    float*    Dp    = (float*)   (ws + OFF_DP);
    float*    wefft = (float*)   (ws + OFF_WT);
    bf16_t*   mt    = (bf16_t*)  (ws + OFF_MT);

    const int tid  = threadIdx.x;
    const int lane = tid & 63;
    const int wv   = tid >> 6;

    __shared__ float kbuf[2][132];

    // ---- Hoisted phase-3 A-operand: read x NOW so HBM latency overlaps
    // phases 1+2. (x is an input; independent of all intermediates.)
    const int mrow = lane & 15;
    const int quad = lane >> 4;
    const int r0   = blockIdx.x * 64 + wv * 16;   // 64 out-rows per block
    bf16x8 af[5];
    {
        const float* xr = x + (r0 + mrow) * OBS + quad * 8;
        #pragma unroll
        for (int kt = 0; kt < 4; ++kt) {
            f32x4 lo = *(const f32x4*)(xr + kt * 32);
            f32x4 hi = *(const f32x4*)(xr + kt * 32 + 4);
            bf16x8 a;
            a[0] = (bf16_t)lo[0]; a[1] = (bf16_t)lo[1];
            a[2] = (bf16_t)lo[2]; a[3] = (bf16_t)lo[3];
            a[4] = (bf16_t)hi[0]; a[5] = (bf16_t)hi[1];
            a[6] = (bf16_t)hi[2]; a[7] = (bf16_t)hi[3];
            af[kt] = a;
        }
        bf16x8 a;
        #pragma unroll
        for (int j = 0; j < 8; ++j) a[j] = (bf16_t)0.f;
        if (quad == 0) a[0] = (bf16_t)1.0f;       // k=128: bias column
        af[4] = a;
    }

    // ---------------- Phase 1: wefft[v][j] = 0.25*sum_h vw[j][h*256+v]; A; Dp
    {
        int j0 = blockIdx.x * 4;            // 4 j-rows per block, 128*4 = 512
        float vals[4];
        #pragma unroll
        for (int jj = 0; jj < 4; ++jj) {
            const float* r = vw + (j0 + jj) * (4 * VSZ);
            vals[jj] = 0.25f * ((r[tid] + r[tid + 256]) + (r[tid + 512] + r[tid + 768]));
        }
        f32x4 o = {vals[0], vals[1], vals[2], vals[3]};
        *(f32x4*)(wefft + tid * HID + j0) = o;

        if (blockIdx.x == 0) {
            // A[opt]: wave wv handles options 4wv..4wv+3
            #pragma unroll
            for (int oo = 0; oo < 4; ++oo) {
                int o_ = wv * 4 + oo;
                float cur = p_w[o_ * NU + lane] + p_b[lane];
                float sum = 0.f;
                #pragma unroll
                for (int t = 0; t < TOPK; ++t) {
                    float m = cur;
                    #pragma unroll
                    for (int off = 32; off >= 1; off >>= 1)
                        m = fmaxf(m, __shfl_xor(m, off));
                    sum += 1.f / (1.f + expf(-m));
                    unsigned long long bal = __ballot(cur == m);
                    int first = __ffsll(bal) - 1;   // lowest index: jax tie-break
                    if (lane == first) cur = -1e30f;
                }
                if (lane == 0) A[o_] = sum * (1.f / NU);
            }
            Dp[tid] = 0.03125f * ((vb[tid] + vb[tid + 256]) + (vb[tid + 512] + vb[tid + 768]));
        }
    }
    gbar(flag0);

    // ---------------- Phase 2: mt[v][k] = sum_j pw[k][j]*wefft[v][j] (+c, +pad)
    {
        int v0 = blockIdx.x * 2;            // 2 v-rows per block
        const float* wfp0 = wefft + v0 * HID + lane * 8;
        const float* wfp1 = wfp0 + HID;
        f32x4 w00 = *(const f32x4*)(wfp0),     w01 = *(const f32x4*)(wfp0 + 4);
        f32x4 w10 = *(const f32x4*)(wfp1),     w11 = *(const f32x4*)(wfp1 + 4);

        for (int it = 0; it < 33; ++it) {
            if (it == 32 && wv != 0) break;             // only wave 0 does c row
            const float* pr = (it < 32) ? (pw + (wv * 32 + it) * HID + lane * 8)
                                        : (pb + lane * 8);
            f32x4 p0 = *(const f32x4*)(pr), p1 = *(const f32x4*)(pr + 4);
            float s0 = ((p0[0]*w00[0] + p0[1]*w00[1]) + (p0[2]*w00[2] + p0[3]*w00[3]))
                     + ((p1[0]*w01[0] + p1[1]*w01[1]) + (p1[2]*w01[2] + p1[3]*w01[3]));
            float s1 = ((p0[0]*w10[0] + p0[1]*w10[1]) + (p0[2]*w10[2] + p0[3]*w10[3]))
                     + ((p1[0]*w11[0] + p1[1]*w11[1]) + (p1[2]*w11[2] + p1[3]*w11[3]));
            #pragma unroll
            for (int off = 32; off >= 1; off >>= 1) {
                s0 += __shfl_xor(s0, off);
                s1 += __shfl_xor(s1, off);
            }
            if (lane == 0) {
                int k = (it < 32) ? (wv * 32 + it) : 128;
                kbuf[0][k] = s0;
                kbuf[1][k] = s1;
            }
        }
        __syncthreads();
        #pragma unroll
        for (int idx = tid; idx < 2 * KEXT; idx += 256) {
            int vv = idx / KEXT;
            int k  = idx - vv * KEXT;
            float val = (k < 129) ? kbuf[vv][k] : 0.f;
            mt[(v0 + vv) * KEXT + k] = (bf16_t)val;
        }
    }
    gbar(flag1);

    // ---------------- Phase 3: out[b][v] = A[opt[b]]*(x'@M')[b][v] + Dp[v]
    {
        // Prefetch per-row scale BEFORE the MFMA loops (dependent gather).
        float av[4];
        #pragma unroll
        for (int r = 0; r < 4; ++r)
            av[r] = A[opt[r0 + quad * 4 + r]];

        #pragma unroll
        for (int half = 0; half < 2; ++half) {
            int c0 = half * 128;
            f32x4 acc[8];
            #pragma unroll
            for (int t = 0; t < 8; ++t) acc[t] = (f32x4){0.f, 0.f, 0.f, 0.f};
            const bf16_t* mb = mt + (c0 + mrow) * KEXT + quad * 8;
            #pragma unroll
            for (int kt = 0; kt < 5; ++kt) {
                #pragma unroll
                for (int t = 0; t < 8; ++t) {
                    bf16x8 b = *(const bf16x8*)(mb + t * 16 * KEXT + kt * 32);
                    acc[t] = __builtin_amdgcn_mfma_f32_16x16x32_bf16(af[kt], b, acc[t], 0, 0, 0);
                }
            }
            // C/D layout: col=lane&15, row=quad*4+reg
            #pragma unroll
            for (int r = 0; r < 4; ++r) {
                int row = r0 + quad * 4 + r;
                float* orow = out + row * VSZ;
                #pragma unroll
                for (int t = 0; t < 8; ++t) {
                    int col = c0 + t * 16 + mrow;
                    orow[col] = av[r] * acc[t][r] + Dp[col];
                }
            }
        }
    }
}

// ---------------------------------------------------------------------------
extern "C" void kernel_launch(void* const* d_in, const int* in_sizes, int n_in,
                              void* d_out, int out_size, void* d_ws, size_t ws_size,
                              hipStream_t stream) {
    const float* x        = (const float*)d_in[0];
    const int*   option   = (const int*)  d_in[1];
    const float* pre_fc_w = (const float*)d_in[2];
    const float* pre_fc_b = (const float*)d_in[3];
    const float* value_w  = (const float*)d_in[4];
    const float* value_b  = (const float*)d_in[5];
    const float* p_w      = (const float*)d_in[6];
    const float* p_b      = (const float*)d_in[7];
    float* out = (float*)d_out;
    char*  ws  = (char*)d_ws;

    // zero both barrier counters (single graph-capturable memset node)
    hipMemsetAsync(ws, 0, 1024, stream);

    k_fused<<<dim3(NBLK), dim3(256), 0, stream>>>(
        x, option, pre_fc_w, pre_fc_b, value_w, value_b, p_w, p_b, out, ws);
}

// Round 6
// 90.520 us; speedup vs baseline: 1.4731x; 1.4663x over previous
//
#include <hip/hip_runtime.h>
#include <hip/hip_bf16.h>

// Problem constants
#define B_N   8192
#define OBS   128
#define HID   512
#define VSZ   256
#define NU    64
#define TOPK  8
#define NOPT  16
#define KEXT  160   // 128 x-cols + 1 bias col + 31 zero pad

typedef __bf16 bf16_t;
typedef __bf16 bf16x8 __attribute__((ext_vector_type(8)));
typedef float  f32x4  __attribute__((ext_vector_type(4)));

// Workspace layout (bytes)
#define OFF_A    0u         // 16 f32
#define OFF_DP   256u       // 256 f32
#define OFF_WT   2048u      // weff[j][v] f32 512x256 = 524288
#define OFF_MT   526336u    // mt[v][k] bf16 256x160 = 81920

// ---------------------------------------------------------------------------
// Kernel 1: weff[j][v] = 0.25 * sum_h value_w[j][h*256+v].  grid 512 x 256.
__global__ void k_pre(const float* __restrict__ vw, float* __restrict__ weff) {
    int j = blockIdx.x, v = threadIdx.x;
    const float* r = vw + j * (4 * VSZ);
    weff[j * VSZ + v] = 0.25f * ((r[v] + r[v + VSZ]) + (r[v + 2 * VSZ] + r[v + 3 * VSZ]));
}

// ---------------------------------------------------------------------------
// Kernel 2: grid 130 x 1024.
//  blocks 0..127: mt[v][k] = sum_j pw[k][j] * weff[j][v]   (k = blockIdx)
//  block  128   : c row (k=128) from pre_fc_b
//  block  129   : pad cols 129..159 = 0; A[16] (waves 4..7); Dp (tids 512..767)
__global__ void k_mt(const float* __restrict__ pw, const float* __restrict__ pb,
                     const float* __restrict__ weff, const float* __restrict__ p_w,
                     const float* __restrict__ p_b, const float* __restrict__ vb,
                     bf16_t* __restrict__ mt, float* __restrict__ A,
                     float* __restrict__ Dp) {
    const int tid = threadIdx.x;
    if (blockIdx.x == 129) {
        // pad columns
        if (tid < VSZ) {
            bf16_t* row = mt + tid * KEXT;
            #pragma unroll
            for (int k = 129; k < KEXT; ++k) row[k] = (bf16_t)0.f;
        }
        // A[opt]: waves 4..7, wave w handles options 4(w-4)..4(w-4)+3
        int wvi = tid >> 6;
        if (wvi >= 4 && wvi < 8) {
            int lane = tid & 63;
            #pragma unroll
            for (int oo = 0; oo < 4; ++oo) {
                int o = (wvi - 4) * 4 + oo;
                float cur = p_w[o * NU + lane] + p_b[lane];
                float sum = 0.f;
                #pragma unroll
                for (int t = 0; t < TOPK; ++t) {
                    float m = cur;
                    #pragma unroll
                    for (int off = 32; off >= 1; off >>= 1)
                        m = fmaxf(m, __shfl_xor(m, off));
                    sum += 1.f / (1.f + expf(-m));
                    unsigned long long bal = __ballot(cur == m);
                    int first = __ffsll(bal) - 1;   // lowest index: jax tie-break
                    if (lane == first) cur = -1e30f;
                }
                if (lane == 0) A[o] = sum * (1.f / NU);
            }
        }
        // Dp[v] = 0.125 * 0.25 * sum_h vb[h*256+v]
        if (tid >= 512 && tid < 768) {
            int v = tid & 255;
            Dp[v] = 0.03125f * ((vb[v] + vb[v + VSZ]) + (vb[v + 2 * VSZ] + vb[v + 3 * VSZ]));
        }
        return;
    }

    // compute blocks: one k-column each (r2-proven body)
    int k  = blockIdx.x;
    int v  = tid & 255;
    int jq = tid >> 8;
    __shared__ float red[1024];
    const float* wr = (k < OBS) ? (pw + k * HID) : pb;
    const float* wj = wr + jq * 128;
    const float* wf = weff + (jq * 128) * VSZ + v;
    float a0 = 0.f, a1 = 0.f, a2 = 0.f, a3 = 0.f;
    #pragma unroll 4
    for (int j = 0; j < 128; j += 4) {
        a0 += wj[j + 0] * wf[(j + 0) * VSZ];
        a1 += wj[j + 1] * wf[(j + 1) * VSZ];
        a2 += wj[j + 2] * wf[(j + 2) * VSZ];
        a3 += wj[j + 3] * wf[(j + 3) * VSZ];
    }
    red[tid] = (a0 + a1) + (a2 + a3);
    __syncthreads();
    if (jq == 0)
        mt[v * KEXT + k] = (bf16_t)(((red[v] + red[v + 256]) + (red[v + 512] + red[v + 768])));
}

// ---------------------------------------------------------------------------
// Kernel 3: out[b][v] = A[opt[b]] * (x' @ M')[b][v] + Dp[v]
// x' = [x | 1 | 0...], M' = [M ; c ; 0...]; K = 160. f32 x -> bf16 in-register.
// MFMA 16x16x32. Block = 4 waves; wave: 16 rows x 128 cols.
// grid (8192/64, 256/128) = (128, 2).
__launch_bounds__(256)
__global__ void k_main(const float* __restrict__ x, const bf16_t* __restrict__ mt,
                       const int* __restrict__ opt, const float* __restrict__ A,
                       const float* __restrict__ Dp, float* __restrict__ out) {
    const int wave = threadIdx.x >> 6;
    const int lane = threadIdx.x & 63;
    const int mrow = lane & 15;
    const int quad = lane >> 4;
    const int r0   = blockIdx.x * 64 + wave * 16;
    const int c0   = blockIdx.y * 128;

    // A-fragments first: all x loads in flight before mt reads
    bf16x8 af[5];
    {
        const float* xr = x + (r0 + mrow) * OBS + quad * 8;
        f32x4 lo[4], hi[4];
        #pragma unroll
        for (int kt = 0; kt < 4; ++kt) {
            lo[kt] = *(const f32x4*)(xr + kt * 32);
            hi[kt] = *(const f32x4*)(xr + kt * 32 + 4);
        }
        #pragma unroll
        for (int kt = 0; kt < 4; ++kt) {
            bf16x8 a;
            a[0] = (bf16_t)lo[kt][0]; a[1] = (bf16_t)lo[kt][1];
            a[2] = (bf16_t)lo[kt][2]; a[3] = (bf16_t)lo[kt][3];
            a[4] = (bf16_t)hi[kt][0]; a[5] = (bf16_t)hi[kt][1];
            a[6] = (bf16_t)hi[kt][2]; a[7] = (bf16_t)hi[kt][3];
            af[kt] = a;
        }
        bf16x8 a;
        #pragma unroll
        for (int j = 0; j < 8; ++j) a[j] = (bf16_t)0.f;
        if (quad == 0) a[0] = (bf16_t)1.0f;   // k=128: bias column
        af[4] = a;
    }

    // per-row scale gathered before the MFMA loop
    float av[4];
    #pragma unroll
    for (int r = 0; r < 4; ++r)
        av[r] = A[opt[r0 + quad * 4 + r]];

    f32x4 acc[8];
    #pragma unroll
    for (int t = 0; t < 8; ++t) acc[t] = (f32x4){0.f, 0.f, 0.f, 0.f};

    const bf16_t* mb = mt + (c0 + mrow) * KEXT + quad * 8;
    #pragma unroll
    for (int kt = 0; kt < 5; ++kt) {
        #pragma unroll
        for (int t = 0; t < 8; ++t) {
            bf16x8 b = *(const bf16x8*)(mb + t * 16 * KEXT + kt * 32);
            acc[t] = __builtin_amdgcn_mfma_f32_16x16x32_bf16(af[kt], b, acc[t], 0, 0, 0);
        }
    }

    // C/D layout: col=lane&15, row=quad*4+reg
    #pragma unroll
    for (int r = 0; r < 4; ++r) {
        int row = r0 + quad * 4 + r;
        float* orow = out + row * VSZ;
        #pragma unroll
        for (int t = 0; t < 8; ++t) {
            int col = c0 + t * 16 + mrow;
            orow[col] = av[r] * acc[t][r] + Dp[col];
        }
    }
}

// ---------------------------------------------------------------------------
extern "C" void kernel_launch(void* const* d_in, const int* in_sizes, int n_in,
                              void* d_out, int out_size, void* d_ws, size_t ws_size,
                              hipStream_t stream) {
    const float* x        = (const float*)d_in[0];
    const int*   option   = (const int*)  d_in[1];
    const float* pre_fc_w = (const float*)d_in[2];
    const float* pre_fc_b = (const float*)d_in[3];
    const float* value_w  = (const float*)d_in[4];
    const float* value_b  = (const float*)d_in[5];
    const float* p_w      = (const float*)d_in[6];
    const float* p_b      = (const float*)d_in[7];
    float* out = (float*)d_out;

    char* ws = (char*)d_ws;
    float*  A    = (float*) (ws + OFF_A);
    float*  Dp   = (float*) (ws + OFF_DP);
    float*  weff = (float*) (ws + OFF_WT);
    bf16_t* mt   = (bf16_t*)(ws + OFF_MT);

    k_pre <<<dim3(HID), dim3(VSZ), 0, stream>>>(value_w, weff);
    k_mt  <<<dim3(130), dim3(1024), 0, stream>>>(pre_fc_w, pre_fc_b, weff,
                                                 p_w, p_b, value_b, mt, A, Dp);
    k_main<<<dim3(B_N / 64, VSZ / 128), dim3(256), 0, stream>>>(x, mt, option, A, Dp, out);
}